// Round 20
// baseline (92.912 us; speedup 1.0000x reference)
//
#include <hip/hip_runtime.h>
#include <math.h>

#define CIN   16
#define COUT  64
#define H     256
#define W     256
#define OH    254
#define OW    254
#define NTAP  9
#define HWSZ  (H * W)
#define RING  14
#define SROW  136        // f16x8 slots per ring row: 2 cin-halves * 68 px

typedef _Float16 f16x8  __attribute__((ext_vector_type(8)));
typedef float    f32x16 __attribute__((ext_vector_type(16)));

// Raw barrier WITHOUT the __syncthreads vmcnt(0) drain: global loads stay in
// flight across it. lgkmcnt(0) orders our ds_writes for other waves.
#define BARRIER()                                                               \
    __builtin_amdgcn_sched_barrier(0);                                          \
    asm volatile("s_waitcnt lgkmcnt(0)" ::: "memory");                          \
    __builtin_amdgcn_s_barrier();                                               \
    __builtin_amdgcn_sched_barrier(0);

// weight pack: [tap 9][msub 2][lane 64][e 8] fp16; co=(l&31)+32m, cin=8*(l>>5)+e
__global__ void wpack_kernel(const float* __restrict__ w, _Float16* __restrict__ wpk) {
    int idx = blockIdx.x * 256 + threadIdx.x;   // 0..9215
    if (idx >= NTAP * 2 * 64 * 8) return;
    int e = idx & 7, l = (idx >> 3) & 63, m = (idx >> 9) & 1, t = idx >> 10;
    int co  = (l & 31) + 32 * m;
    int cin = 8 * (l >> 5) + e;
    wpk[idx] = (_Float16)w[((co * CIN + cin) * 3 + t / 3) * 3 + (t % 3)];
}

__device__ __forceinline__ float tanh_fast(float v) {
    float e = __expf(2.0f * v);
    return 1.0f - 2.0f * __builtin_amdgcn_rcpf(e + 1.0f);
}
__device__ __forceinline__ float min3f(float a, float b, float c) {
    return fminf(fminf(a, b), c);   // clang fuses to v_min3_f32
}

// 256 thr = 4 waves (2 px-slices x 2 row-groups, full 64-cout per wave).
// Persistent block = (img, 64px col, 128-row half); 32 tiles of 4 out-rows.
// DEPTH-2 register prefetch: tile t PWRITEs rows 4t+10..13 (loaded at t-2)
// and PLOADs rows 4t+18..21 (for t+2) -> ~2x outstanding bytes at all times.
__global__ __launch_bounds__(256, 2) void conv_mfma_kernel(
        const float* __restrict__ x, const f16x8* __restrict__ wpk,
        const float* __restrict__ bias, float* __restrict__ out) {
    __shared__ f16x8 ring[RING * SROW];    // 30,464 B
    __shared__ float bias_lds[64];         // [g2][m][q] pre-arranged

    const int tid  = threadIdx.x;
    const int lane = tid & 63;

    int bid = blockIdx.x;
    int nb  = (bid & 7) * 64 + (bid >> 3);     // 512 = 8*64 bijective XCD swizzle
    const int img  = nb >> 3;
    const int rem  = nb & 7;
    const int colb = rem & 3;                  // 64-px column
    const int half = rem >> 2;                 // 128-row half
    const int base = 64 * colb;
    const int R0   = 128 * half;

    const float* xb = x + (size_t)img * CIN * HWSZ;

    // ---- weights: full 64 cout -> 72 VGPRs ----
    f16x8 wreg[NTAP][2];
#pragma unroll
    for (int t = 0; t < NTAP; ++t)
#pragma unroll
        for (int m = 0; m < 2; ++m)
            wreg[t][m] = wpk[(t * 2 + m) * 64 + lane];

    // bias -> LDS lane layout
    if (tid < 64) {
        int q = tid & 15, m = (tid >> 4) & 1, g = tid >> 5;
        bias_lds[tid] = bias[(q & 3) + 8 * (q >> 2) + 4 * g + 32 * m];
    }

    // ---- staging unit decode: u = tid + 256k over [row4 0..3][r2 0..67] ----
    int r4[2], gq[2], gx[2], wof[2];
#pragma unroll
    for (int k = 0; k < 2; ++k) {
        int u  = tid + 256 * k;
        r4[k]  = u / 68;
        int r2 = u - 68 * r4[k];
        int g  = (r2 >= 34) ? 1 : 0;
        int p  = r2 - 34 * g;
        int px = base + 2 * p; if (px > 254) px = 254;
        gq[k]  = g;
        gx[k]  = px;
        wof[k] = g * 68 + 2 * p;
    }
    const bool act1 = (tid < 16);              // 272 - 256 units

    float2 vA0[8], vA1[8], vB0[8], vB1[8];     // depth-2 sets (A: even t, B: odd)

#define PLOADK(k, rowAbs, vv)                                                   \
    {                                                                           \
        int gr = (rowAbs); if (gr > 255) gr = 255;                              \
        const float* gp = xb + (size_t)(8 * gq[k]) * HWSZ + (size_t)gr * W + gx[k]; \
        _Pragma("unroll")                                                       \
        for (int cc = 0; cc < 8; ++cc) vv[cc] = *(const float2*)(gp + (size_t)cc * HWSZ); \
    }

#define PWRITEK(k, slot, vv)                                                    \
    {                                                                           \
        f16x8 q0, q1;                                                           \
        _Pragma("unroll")                                                       \
        for (int cc = 0; cc < 8; ++cc) { q0[cc] = (_Float16)vv[cc].x;           \
                                         q1[cc] = (_Float16)vv[cc].y; }         \
        const int ad = (slot) * SROW + wof[k];                                  \
        ring[ad]     = q0;                                                      \
        ring[ad + 1] = q1;                                                      \
    }

#define SLOT(rowAbs) ((rowAbs) % RING)

    // ---- prologue: stage rows R0..R0+9 (680 units over 3 rounds) ----
#pragma unroll
    for (int k = 0; k < 3; ++k) {
        int u = tid + 256 * k;
        if (k == 2 && tid >= 168) break;
        int r10 = u / 68;
        int r2  = u - 68 * r10;
        int g   = (r2 >= 34) ? 1 : 0;
        int p   = r2 - 34 * g;
        int px  = base + 2 * p; if (px > 254) px = 254;
        const float* gp = xb + (size_t)(8 * g) * HWSZ + (size_t)(R0 + r10) * W + px;
        float2 vm[8];
#pragma unroll
        for (int cc = 0; cc < 8; ++cc) vm[cc] = *(const float2*)(gp + (size_t)cc * HWSZ);
        f16x8 q0, q1;
#pragma unroll
        for (int cc = 0; cc < 8; ++cc) { q0[cc] = (_Float16)vm[cc].x;
                                         q1[cc] = (_Float16)vm[cc].y; }
        const int ad = SLOT(R0 + r10) * SROW + g * 68 + 2 * p;
        ring[ad]     = q0;
        ring[ad + 1] = q1;
    }

    // initial depth-2 prefetch: set A = rows R0+10..13, set B = rows R0+14..17
    PLOADK(0, R0 + 10 + r4[0], vA0)
    if (act1) PLOADK(1, R0 + 10 + r4[1], vA1)
    PLOADK(0, R0 + 14 + r4[0], vB0)
    if (act1) PLOADK(1, R0 + 14 + r4[1], vB1)
    BARRIER()

    const int wv  = tid >> 6;
    const int s   = wv & 1;                    // 32-px slice
    const int rg  = wv >> 1;                   // 2-row group
    const int l31 = lane & 31;
    const int g2  = lane >> 5;
    const int foff = g2 * 68 + 32 * s + l31;
    const int opx  = base + 32 * s + l31;
    const size_t obase = (size_t)img * OH * OW;
    const f32x16* bp = (const f32x16*)(bias_lds + g2 * 32);

#define COMPUTE_TILE(t)                                                         \
    {                                                                           \
        const int row0 = R0 + 4 * (t);                                          \
        const int rowoff = 2 * rg;                                              \
        f32x16 cb0 = bp[0], cb1 = bp[1];                                        \
        f32x16 acc[2][2];                                                       \
        _Pragma("unroll")                                                       \
        for (int dd = 0; dd < 4; ++dd) {                                        \
            const f16x8* rp = ring + SLOT(row0 + rowoff + dd) * SROW + foff;    \
            f16x8 f0 = rp[0], f1 = rp[1], f2 = rp[2];                           \
            _Pragma("unroll")                                                   \
            for (int kw = 0; kw < 3; ++kw) {                                    \
                f16x8 ff = (kw == 0) ? f0 : (kw == 1) ? f1 : f2;                \
                _Pragma("unroll")                                               \
                for (int ro = 0; ro < 2; ++ro) {                                \
                    const int kh = dd - ro;                                     \
                    if (kh < 0 || kh > 2) continue;                             \
                    _Pragma("unroll")                                           \
                    for (int m = 0; m < 2; ++m) {                               \
                        const f32x16& ci = (kh == 0 && kw == 0)                 \
                                         ? (m == 0 ? cb0 : cb1) : acc[ro][m];   \
                        acc[ro][m] = __builtin_amdgcn_mfma_f32_32x32x16_f16(    \
                            wreg[kh * 3 + kw][m], ff, ci, 0, 0, 0);             \
                    }                                                           \
                }                                                               \
            }                                                                   \
        }                                                                       \
        _Pragma("unroll")                                                       \
        for (int ro = 0; ro < 2; ++ro) {                                        \
            float mn = fminf(acc[ro][0][0], acc[ro][1][0]);                     \
            _Pragma("unroll")                                                   \
            for (int q = 1; q < 16; ++q)                                        \
                mn = min3f(acc[ro][0][q], acc[ro][1][q], mn);                   \
            mn = fminf(mn, __shfl_xor(mn, 32));                                 \
            float t2 = tanh_fast(tanh_fast(mn));                                \
            const int oh = row0 + rowoff + ro;                                  \
            if (g2 == 0 && oh < OH && opx < OW)                                 \
                out[obase + (size_t)oh * OW + opx] = t2;                        \
        }                                                                       \
    }

#pragma unroll 1
    for (int j = 0; j < 16; ++j) {
        const int t0 = 2 * j, t1 = 2 * j + 1;
        // ---- even tile: compute, write set A (rows 4t0+10..13), reload A (+18..21)
        COMPUTE_TILE(t0)
        {
            const int wr = R0 + 4 * t0 + 10;
            PWRITEK(0, SLOT(wr + r4[0]), vA0)
            if (act1) PWRITEK(1, SLOT(wr + r4[1]), vA1)
            PLOADK(0, wr + 8 + r4[0], vA0)
            if (act1) PLOADK(1, wr + 8 + r4[1], vA1)
        }
        BARRIER()
        // ---- odd tile: compute, write set B, reload B
        COMPUTE_TILE(t1)
        {
            const int wr = R0 + 4 * t1 + 10;
            PWRITEK(0, SLOT(wr + r4[0]), vB0)
            if (act1) PWRITEK(1, SLOT(wr + r4[1]), vB1)
            PLOADK(0, wr + 8 + r4[0], vB0)
            if (act1) PLOADK(1, wr + 8 + r4[1], vB1)
        }
        BARRIER()
    }
}

extern "C" void kernel_launch(void* const* d_in, const int* in_sizes, int n_in,
                              void* d_out, int out_size, void* d_ws, size_t ws_size,
                              hipStream_t stream) {
    const float* x    = (const float*)d_in[0];
    const float* w    = (const float*)d_in[1];
    const float* bias = (const float*)d_in[2];
    float* out = (float*)d_out;
    _Float16* wpk = (_Float16*)d_ws;   // 9216 fp16 = 18,432 B

    wpack_kernel<<<36, 256, 0, stream>>>(w, wpk);
    conv_mfma_kernel<<<512, 256, 0, stream>>>(x, (const f16x8*)wpk, bias, out);
}